// Round 3
// baseline (114.294 us; speedup 1.0000x reference)
//
#include <hip/hip_runtime.h>

// Masked cross-attention: out = softmax(where(mask_bool, (Q K^T / 8) * mask_scale, -inf)) V
// B=4, SQ=4096, SK=308, H=8, DH=64. fp32 in/out, f16 MFMA internally.
//
// Strategy: memory-bound on mask_scale+mask_bool streams (~323 MB). One WG per
// (b,h,128-q rows); K,V staged once per WG into LDS in MFMA-fragment lane order.
// Swapped QK^T (S^T = K·Q^T) so P's C-layout == A-layout of 16x16x16 f16 MFMA.

#define NB     4
#define NSQ    4096
#define NSK    308
#define NH     8
#define NDH    64
#define NINNER 512
#define NKT    20          // ceil(308/16)
#define QTILE  128         // q rows per workgroup (8 waves x 16)
#define NTHREADS 512
#define LDS_BYTES ((NKT*2*64*8 + NKT*4*64*4) * 2)   // 40KB K + 40KB V (f16)

typedef _Float16 h8 __attribute__((ext_vector_type(8)));
typedef _Float16 h4 __attribute__((ext_vector_type(4)));
typedef float    f4 __attribute__((ext_vector_type(4)));
typedef int      i4 __attribute__((ext_vector_type(4)));

__global__ __launch_bounds__(NTHREADS) void omost_attn(
    const float* __restrict__ Qg, const float* __restrict__ Kg,
    const float* __restrict__ Vg, const float* __restrict__ MSg,
    const int*   __restrict__ MBg, float* __restrict__ Og)
{
  extern __shared__ __align__(16) _Float16 smem[];
  _Float16* Klds = smem;                    // [kt][dhc][lane][8] f16, 16B/slot
  _Float16* Vlds = smem + NKT*2*64*8;       // [kt][nt][lane][4]  f16,  8B/slot

  const int tid  = threadIdx.x;
  const int lane = tid & 63;
  const int wv   = tid >> 6;      // wave 0..7
  const int lg   = lane >> 4;     // lane group 0..3
  const int lr   = lane & 15;

  const int wg = blockIdx.x;
  const int qt = wg & (NSQ / QTILE - 1);    // 0..31
  const int bh = wg >> 5;
  const int b  = bh >> 3;
  const int h  = bh & 7;

  // ---- stage K: A-fragments of mfma_f32_16x16x32_f16 ----
  // slot s=(kt,dhc,l): K[kt*16+(l&15)][dhc*32+(l>>4)*8 + 0..7]
  const float* Kb = Kg + (size_t)b * NSK * NINNER + h * NDH;
  #pragma unroll
  for (int i = 0; i < (NKT*2*64) / NTHREADS; ++i) {   // 5 iters
    int s   = tid + i * NTHREADS;
    int l   = s & 63;
    int dhc = (s >> 6) & 1;
    int kt  = s >> 7;
    int row = kt * 16 + (l & 15);
    int col = dhc * 32 + ((l >> 4) << 3);
    h8 hk;
    #pragma unroll
    for (int j = 0; j < 8; ++j) hk[j] = (_Float16)0.f;
    if (row < NSK) {
      const float* p = Kb + (size_t)row * NINNER + col;
      f4 a = *(const f4*)p;
      f4 c = *(const f4*)(p + 4);
      hk[0]=(_Float16)a[0]; hk[1]=(_Float16)a[1]; hk[2]=(_Float16)a[2]; hk[3]=(_Float16)a[3];
      hk[4]=(_Float16)c[0]; hk[5]=(_Float16)c[1]; hk[6]=(_Float16)c[2]; hk[7]=(_Float16)c[3];
    }
    *(h8*)(Klds + (size_t)s * 8) = hk;
  }

  // ---- stage V: B-fragments of mfma_f32_16x16x16f16 ----
  // slot s=(kt,nt,l): V[kt*16+(l>>4)*4 + 0..3][nt*16+(l&15)]
  const float* Vb = Vg + (size_t)b * NSK * NINNER + h * NDH;
  #pragma unroll
  for (int i = 0; i < (NKT*4*64) / NTHREADS; ++i) {   // 10 iters
    int s    = tid + i * NTHREADS;
    int l    = s & 63;
    int nt   = (s >> 6) & 3;
    int kt   = s >> 8;
    int col  = nt * 16 + (l & 15);
    int row0 = kt * 16 + ((l >> 4) << 2);
    h4 hv;
    #pragma unroll
    for (int j = 0; j < 4; ++j) hv[j] = (_Float16)0.f;
    #pragma unroll
    for (int j = 0; j < 4; ++j) {
      int row = row0 + j;
      if (row < NSK) hv[j] = (_Float16)Vb[(size_t)row * NINNER + col];
    }
    *(h4*)(Vlds + (size_t)s * 4) = hv;
  }
  __syncthreads();

  const float NEG_INF = -__builtin_inff();

  // ---- per-wave Q fragments (B operand of S^T = K · Q^T) ----
  // lane holds Q[q0 + (lane&15)][dhc*32 + (lane>>4)*8 + 0..7]
  const int q0   = qt * QTILE + wv * 16;
  const int qrow = q0 + lr;
  const float* Qb = Qg + ((size_t)b * NSQ + qrow) * NINNER + h * NDH;
  h8 qf[2];
  #pragma unroll
  for (int dhc = 0; dhc < 2; ++dhc) {
    const float* p = Qb + dhc * 32 + lg * 8;
    f4 a = *(const f4*)p;
    f4 c = *(const f4*)(p + 4);
    h8 t;
    t[0]=(_Float16)a[0]; t[1]=(_Float16)a[1]; t[2]=(_Float16)a[2]; t[3]=(_Float16)a[3];
    t[4]=(_Float16)c[0]; t[5]=(_Float16)c[1]; t[6]=(_Float16)c[2]; t[7]=(_Float16)c[3];
    qf[dhc] = t;
  }

  // ---- S^T tiles: D[k][q], lane holds q=q0+(l&15), k=kt*16+(l>>4)*4+r ----
  f4 S[NKT];
  const h8* Kf = (const h8*)Klds;
  #pragma unroll
  for (int kt = 0; kt < NKT; ++kt) {
    f4 c = {0.f, 0.f, 0.f, 0.f};
    c = __builtin_amdgcn_mfma_f32_16x16x32_f16(Kf[(kt*2+0)*64 + lane], qf[0], c, 0, 0, 0);
    c = __builtin_amdgcn_mfma_f32_16x16x32_f16(Kf[(kt*2+1)*64 + lane], qf[1], c, 0, 0, 0);
    S[kt] = c;
  }

  // ---- mask + softmax over k ----
  const size_t mrow = ((size_t)bh * NSQ + qrow) * NSK;
  float rmax = NEG_INF;
  #pragma unroll
  for (int kt = 0; kt < NKT; ++kt) {
    int kb = kt * 16 + lg * 4;
    f4 s = S[kt];
    if (kb + 4 <= NSK) {               // uniform except kt=19 lane-groups 1..3
      f4 sc = *(const f4*)(MSg + mrow + kb);
      i4 mb = *(const i4*)(MBg + mrow + kb);
      #pragma unroll
      for (int r = 0; r < 4; ++r)
        s[r] = mb[r] ? s[r] * 0.125f * sc[r] : NEG_INF;
    } else {
      #pragma unroll
      for (int r = 0; r < 4; ++r) s[r] = NEG_INF;
    }
    #pragma unroll
    for (int r = 0; r < 4; ++r) rmax = fmaxf(rmax, s[r]);
    S[kt] = s;
  }
  rmax = fmaxf(rmax, __shfl_xor(rmax, 16, 64));
  rmax = fmaxf(rmax, __shfl_xor(rmax, 32, 64));
  float ssum = 0.f;
  #pragma unroll
  for (int kt = 0; kt < NKT; ++kt) {
    f4 s = S[kt];
    #pragma unroll
    for (int r = 0; r < 4; ++r) { float p = __expf(s[r] - rmax); s[r] = p; ssum += p; }
    S[kt] = s;
  }
  ssum += __shfl_xor(ssum, 16, 64);
  ssum += __shfl_xor(ssum, 32, 64);
  const float inv = 1.f / ssum;

  // ---- O = P · V : P's C-layout == A-layout of 16x16x16 f16 MFMA ----
  f4 acc[4];
  #pragma unroll
  for (int nt = 0; nt < 4; ++nt) acc[nt] = (f4){0.f, 0.f, 0.f, 0.f};
  const h4* Vf = (const h4*)Vlds;
  #pragma unroll
  for (int kt = 0; kt < NKT; ++kt) {
    h4 pa;
    #pragma unroll
    for (int r = 0; r < 4; ++r) pa[r] = (_Float16)(S[kt][r] * inv);
    #pragma unroll
    for (int nt = 0; nt < 4; ++nt)
      acc[nt] = __builtin_amdgcn_mfma_f32_16x16x16f16(pa, Vf[(kt*4+nt)*64 + lane], acc[nt], 0, 0, 0);
  }

  // ---- store: lane holds O[q0 + (l>>4)*4 + r][nt*16 + (l&15)] ----
  float* Ob = Og + (size_t)b * NSQ * NINNER + h * NDH;
  #pragma unroll
  for (int nt = 0; nt < 4; ++nt) {
    #pragma unroll
    for (int r = 0; r < 4; ++r) {
      int qq = q0 + lg * 4 + r;
      Ob[(size_t)qq * NINNER + nt * 16 + lr] = acc[nt][r];
    }
  }
}

extern "C" void kernel_launch(void* const* d_in, const int* in_sizes, int n_in,
                              void* d_out, int out_size, void* d_ws, size_t ws_size,
                              hipStream_t stream) {
  const float* Qg  = (const float*)d_in[0];
  const float* Kg  = (const float*)d_in[1];
  const float* Vg  = (const float*)d_in[2];
  const float* MSg = (const float*)d_in[3];
  const int*   MBg = (const int*)d_in[4];
  float* Og = (float*)d_out;

  // 80KB dynamic LDS exceeds the 64KB default cap on some HIP paths; raise it.
  // Host-side attribute set (no alloc/sync) — graph-capture-safe, deterministic.
  static_assert(LDS_BYTES <= 160 * 1024, "exceeds gfx950 LDS");
  (void)hipFuncSetAttribute((const void*)omost_attn,
                            hipFuncAttributeMaxDynamicSharedMemorySize, LDS_BYTES);

  const int nwg = NB * NH * (NSQ / QTILE);   // 1024
  omost_attn<<<dim3(nwg), dim3(NTHREADS), LDS_BYTES, stream>>>(Qg, Kg, Vg, MSg, MBg, Og);
}

// Round 5
// 112.374 us; speedup vs baseline: 1.0171x; 1.0171x over previous
//
#include <hip/hip_runtime.h>

// Masked cross-attention: out = softmax(where(mask_bool, (Q K^T / 8) * mask_scale, -inf)) V
// B=4, SQ=4096, SK=308, H=8, DH=64. fp32 in/out, f16 MFMA internally.
//
// R5 (bisection): R3's exact numerics (two-pass max softmax, pa normalized BEFORE PV)
// + R4's mask-load restructure only (early PF-deep prefetch, rolling buffer fused
// into the QK loop). Decides whether R4's failure was the fusion numerics or the
// prefetch logic.

#define NB     4
#define NSQ    4096
#define NSK    308
#define NH     8
#define NDH    64
#define NINNER 512
#define NKT    20          // ceil(308/16)
#define QTILE  128         // q rows per workgroup (8 waves x 16)
#define NTHREADS 512
#define PF     4           // mask prefetch depth (register tiles)
#define LDS_BYTES ((NKT*2*64*8 + NKT*4*64*4) * 2)   // 40KB K + 40KB V (f16)

typedef _Float16 h8 __attribute__((ext_vector_type(8)));
typedef _Float16 h4 __attribute__((ext_vector_type(4)));
typedef float    f4 __attribute__((ext_vector_type(4)));
typedef int      i4 __attribute__((ext_vector_type(4)));

__global__ __launch_bounds__(NTHREADS) void omost_attn(
    const float* __restrict__ Qg, const float* __restrict__ Kg,
    const float* __restrict__ Vg, const float* __restrict__ MSg,
    const int*   __restrict__ MBg, float* __restrict__ Og)
{
  extern __shared__ __align__(16) _Float16 smem[];
  _Float16* Klds = smem;                    // [kt][dhc][lane][8] f16, 16B/slot
  _Float16* Vlds = smem + NKT*2*64*8;       // [kt][nt][lane][4]  f16,  8B/slot

  const int tid  = threadIdx.x;
  const int lane = tid & 63;
  const int wv   = tid >> 6;      // wave 0..7
  const int lg   = lane >> 4;     // lane group 0..3
  const int lr   = lane & 15;

  const int wg = blockIdx.x;
  const int qt = wg & (NSQ / QTILE - 1);    // 0..31
  const int bh = wg >> 5;
  const int b  = bh >> 3;
  const int h  = bh & 7;

  const int q0   = qt * QTILE + wv * 16;
  const int qrow = q0 + lr;
  const size_t mrow = ((size_t)bh * NSQ + qrow) * NSK;   // 16B-aligned (308%4==0)

  // ---- issue first PF mask tiles; they complete under K/V staging ----
  f4 msb[PF];
  i4 mbb[PF];
  #pragma unroll
  for (int d = 0; d < PF; ++d) {            // kb max = 3*16+12 = 60 < 304: no clamp
    int kb = d * 16 + lg * 4;
    msb[d] = *(const f4*)(MSg + mrow + kb);
    mbb[d] = *(const i4*)(MBg + mrow + kb);
  }

  // ---- stage K: A-fragments of mfma_f32_16x16x32_f16 ----
  // slot s=(kt,dhc,l): K[kt*16+(l&15)][dhc*32+(l>>4)*8 + 0..7]
  const float* Kb = Kg + (size_t)b * NSK * NINNER + h * NDH;
  #pragma unroll
  for (int i = 0; i < (NKT*2*64) / NTHREADS; ++i) {   // 5 iters
    int s   = tid + i * NTHREADS;
    int l   = s & 63;
    int dhc = (s >> 6) & 1;
    int kt  = s >> 7;
    int row = kt * 16 + (l & 15);
    int col = dhc * 32 + ((l >> 4) << 3);
    h8 hk;
    #pragma unroll
    for (int j = 0; j < 8; ++j) hk[j] = (_Float16)0.f;
    if (row < NSK) {
      const float* p = Kb + (size_t)row * NINNER + col;
      f4 a = *(const f4*)p;
      f4 c = *(const f4*)(p + 4);
      hk[0]=(_Float16)a[0]; hk[1]=(_Float16)a[1]; hk[2]=(_Float16)a[2]; hk[3]=(_Float16)a[3];
      hk[4]=(_Float16)c[0]; hk[5]=(_Float16)c[1]; hk[6]=(_Float16)c[2]; hk[7]=(_Float16)c[3];
    }
    *(h8*)(Klds + (size_t)s * 8) = hk;
  }

  // ---- stage V: B-fragments of mfma_f32_16x16x16f16 ----
  // slot s=(kt,nt,l): V[kt*16+(l>>4)*4 + 0..3][nt*16+(l&15)]
  const float* Vb = Vg + (size_t)b * NSK * NINNER + h * NDH;
  #pragma unroll
  for (int i = 0; i < (NKT*4*64) / NTHREADS; ++i) {   // 10 iters
    int s    = tid + i * NTHREADS;
    int l    = s & 63;
    int nt   = (s >> 6) & 3;
    int kt   = s >> 8;
    int col  = nt * 16 + (l & 15);
    int row0 = kt * 16 + ((l >> 4) << 2);
    h4 hv;
    #pragma unroll
    for (int j = 0; j < 4; ++j) hv[j] = (_Float16)0.f;
    #pragma unroll
    for (int j = 0; j < 4; ++j) {
      int row = row0 + j;
      if (row < NSK) hv[j] = (_Float16)Vb[(size_t)row * NINNER + col];
    }
    *(h4*)(Vlds + (size_t)s * 4) = hv;
  }
  __syncthreads();

  const float NEG_INF = -__builtin_inff();

  // ---- per-wave Q fragments (unscaled, R3-verbatim) ----
  // lane holds Q[q0 + (lane&15)][dhc*32 + (lane>>4)*8 + 0..7]
  const float* Qb = Qg + ((size_t)b * NSQ + qrow) * NINNER + h * NDH;
  h8 qf[2];
  #pragma unroll
  for (int dhc = 0; dhc < 2; ++dhc) {
    const float* p = Qb + dhc * 32 + lg * 8;
    f4 a = *(const f4*)p;
    f4 c = *(const f4*)(p + 4);
    h8 t;
    t[0]=(_Float16)a[0]; t[1]=(_Float16)a[1]; t[2]=(_Float16)a[2]; t[3]=(_Float16)a[3];
    t[4]=(_Float16)c[0]; t[5]=(_Float16)c[1]; t[6]=(_Float16)c[2]; t[7]=(_Float16)c[3];
    qf[dhc] = t;
  }

  // ---- fused QK^T + mask loop (prefetched masks), scores kept in registers ----
  // S^T lane layout: q = q0+(l&15), k = kt*16 + (l>>4)*4 + r
  f4 S[NKT];
  float rmax = NEG_INF;
  const h8* Kf = (const h8*)Klds;
  #pragma unroll
  for (int kt = 0; kt < NKT; ++kt) {
    f4 ms = msb[kt % PF];
    i4 mb = mbb[kt % PF];
    if (kt + PF < NKT) {                    // prefetch PF tiles ahead (clamped)
      int kb  = (kt + PF) * 16 + lg * 4;
      int kbl = kb > (NSK - 4) ? (NSK - 4) : kb;
      msb[(kt + PF) % PF] = *(const f4*)(MSg + mrow + kbl);
      mbb[(kt + PF) % PF] = *(const i4*)(MBg + mrow + kbl);
    }
    f4 c = {0.f, 0.f, 0.f, 0.f};
    c = __builtin_amdgcn_mfma_f32_16x16x32_f16(Kf[(kt*2+0)*64 + lane], qf[0], c, 0, 0, 0);
    c = __builtin_amdgcn_mfma_f32_16x16x32_f16(Kf[(kt*2+1)*64 + lane], qf[1], c, 0, 0, 0);

    const int kb0 = kt * 16 + lg * 4;
    f4 s;
    #pragma unroll
    for (int r = 0; r < 4; ++r) {
      bool ok = (kb0 + r < NSK) && (mb[r] != 0);
      s[r] = ok ? c[r] * 0.125f * ms[r] : NEG_INF;
      rmax = fmaxf(rmax, s[r]);
    }
    S[kt] = s;
  }

  // ---- softmax (R3-verbatim): true max, exp, sum, normalize before PV ----
  rmax = fmaxf(rmax, __shfl_xor(rmax, 16, 64));
  rmax = fmaxf(rmax, __shfl_xor(rmax, 32, 64));
  float ssum = 0.f;
  #pragma unroll
  for (int kt = 0; kt < NKT; ++kt) {
    f4 s = S[kt];
    #pragma unroll
    for (int r = 0; r < 4; ++r) { float p = __expf(s[r] - rmax); s[r] = p; ssum += p; }
    S[kt] = s;
  }
  ssum += __shfl_xor(ssum, 16, 64);
  ssum += __shfl_xor(ssum, 32, 64);
  const float inv = 1.f / ssum;

  // ---- O = P · V : P's C-layout == A-layout of 16x16x16 f16 MFMA ----
  f4 acc[4];
  #pragma unroll
  for (int nt = 0; nt < 4; ++nt) acc[nt] = (f4){0.f, 0.f, 0.f, 0.f};
  const h4* Vf = (const h4*)Vlds;
  #pragma unroll
  for (int kt = 0; kt < NKT; ++kt) {
    h4 pa;
    #pragma unroll
    for (int r = 0; r < 4; ++r) pa[r] = (_Float16)(S[kt][r] * inv);
    #pragma unroll
    for (int nt = 0; nt < 4; ++nt)
      acc[nt] = __builtin_amdgcn_mfma_f32_16x16x16f16(pa, Vf[(kt*4+nt)*64 + lane], acc[nt], 0, 0, 0);
  }

  // ---- store: lane holds O[q0 + (l>>4)*4 + r][nt*16 + (l&15)] ----
  float* Ob = Og + (size_t)b * NSQ * NINNER + h * NDH;
  #pragma unroll
  for (int nt = 0; nt < 4; ++nt) {
    #pragma unroll
    for (int r = 0; r < 4; ++r) {
      int qq = q0 + lg * 4 + r;
      Ob[(size_t)qq * NINNER + nt * 16 + lr] = acc[nt][r];
    }
  }
}

extern "C" void kernel_launch(void* const* d_in, const int* in_sizes, int n_in,
                              void* d_out, int out_size, void* d_ws, size_t ws_size,
                              hipStream_t stream) {
  const float* Qg  = (const float*)d_in[0];
  const float* Kg  = (const float*)d_in[1];
  const float* Vg  = (const float*)d_in[2];
  const float* MSg = (const float*)d_in[3];
  const int*   MBg = (const int*)d_in[4];
  float* Og = (float*)d_out;

  // 80KB dynamic LDS exceeds the 64KB default cap; raise it (host-side, capture-safe).
  static_assert(LDS_BYTES <= 160 * 1024, "exceeds gfx950 LDS");
  (void)hipFuncSetAttribute((const void*)omost_attn,
                            hipFuncAttributeMaxDynamicSharedMemorySize, LDS_BYTES);

  const int nwg = NB * NH * (NSQ / QTILE);   // 1024
  omost_attn<<<dim3(nwg), dim3(NTHREADS), LDS_BYTES, stream>>>(Qg, Kg, Vg, MSg, MBg, Og);
}